// Round 9
// baseline (2169.337 us; speedup 1.0000x reference)
//
#include <hip/hip_runtime.h>
#include <cstdint>
#include <cstddef>

typedef __attribute__((ext_vector_type(8))) short short8;
typedef __attribute__((ext_vector_type(4))) float f32x4;
typedef __attribute__((ext_vector_type(4))) unsigned int u32x4;

union U4S8 { u32x4 u; short8 s; unsigned w[4]; };

#define TSTEPS 199

#define WF_PLANE 786432u    // u32x4 per main plane (128 slices x 96 kt x 64 lanes)
#define WR_BASE  1572864u   // u32x4 index where readout frags start
#define WR_PLANE 12288u     // 3 slices x 64 kt x 64 lanes (hi plane; lo follows)

// ---- workspace layout (bytes) ----
#define WS_BAR    0u          // final-reduce counters (per mh)
#define WS_ZROLL  4096u       // 8 slots x 2 mh x 64 rows x 128 ns u32 (tag<<16|m16) = 512 KB
#define WS_FIN    528384u     // 128 x 32 f32 voMax = 16 KB
#define WS_XSB    544768u     // 199 x 128 x 128 B encoder bits
#define WS_WF     3805184u    // (1572864 + 2*12288) x 16 B fragments
#define WS_NEED   29364224u

#define AT_RLX __ATOMIC_RELAXED
#define SC_AGT __HIP_MEMORY_SCOPE_AGENT

// ---------------- encoder: constant-current LIF -> spike bit rows ----------------
extern "C" __global__ __launch_bounds__(1024) void k_encode(
    const float* __restrict__ x, unsigned char* __restrict__ xsb)
{
  const int b = blockIdx.x;
  const int tid = threadIdx.x;
  const float xv = (tid < 512) ? x[b * 512 + tid] : x[b * 512 + tid - 512];
  const float I = (tid < 512) ? fmaxf(__fmul_rn(50.0f, xv), 0.0f)
                              : fmaxf(__fmul_rn(-50.0f, xv), 0.0f);
  float v = 0.0f;
  unsigned long long* dst =
      (unsigned long long*)(xsb + (size_t)b * 128u + (size_t)(tid >> 6) * 8u);
  for (int t = 0; t < TSTEPS; ++t) {
    v = __fadd_rn(v, __fmul_rn(0.1f, __fsub_rn(I, v)));
    const bool z = v > 1.0f;
    if (z) v = 0.0f;
    const unsigned long long m = __ballot(z ? 1 : 0);
    if ((tid & 63) == 0) dst[(size_t)t * 2048u] = m;
  }
}

// ---------------- weight prep: hi/lo bf16 split into MFMA-fragment order ----------------
__device__ __forceinline__ unsigned bf16rne(float f) {
  const unsigned u = __float_as_uint(f);
  return ((u + 0x7FFFu + ((u >> 16) & 1u)) >> 16) & 0xFFFFu;
}

extern "C" __global__ __launch_bounds__(256) void k_prep(
    const float* __restrict__ w_rec, const float* __restrict__ w_in,
    const float* __restrict__ w_out, const float* __restrict__ w_li,
    u32x4* __restrict__ wf)
{
  const unsigned idx  = blockIdx.x * 256u + threadIdx.x;
  const unsigned lane = idx & 63u;
  if (idx < 786432u) {
    const unsigned kt = (idx >> 6) % 96u;
    const unsigned ns = idx / 6144u;
    const unsigned j  = ns * 16u + (lane & 15u);
    const unsigned k0 = kt * 32u + (lane >> 4) * 8u;
    unsigned hi[4], lo[4];
#pragma unroll
    for (int u2 = 0; u2 < 4; ++u2) {
      unsigned hb[2], lb[2];
#pragma unroll
      for (int c = 0; c < 2; ++c) {
        const unsigned k = k0 + 2u * (unsigned)u2 + (unsigned)c;
        float w;
        if (k < 2048u) w = (k == j) ? 0.0f : w_rec[(size_t)j * 2048u + k];
        else           w = w_in[(size_t)j * 1024u + (k - 2048u)];
        const unsigned h = bf16rne(w);
        const float hvf = __uint_as_float(h << 16);
        const unsigned l = bf16rne(__fsub_rn(w, hvf));
        hb[c] = h; lb[c] = l;
      }
      hi[u2] = hb[0] | (hb[1] << 16);
      lo[u2] = lb[0] | (lb[1] << 16);
    }
    u32x4 vh, vl;
    vh[0]=hi[0]; vh[1]=hi[1]; vh[2]=hi[2]; vh[3]=hi[3];
    vl[0]=lo[0]; vl[1]=lo[1]; vl[2]=lo[2]; vl[3]=lo[3];
    wf[idx] = vh;
    wf[idx + WF_PLANE] = vl;
  } else if (idx < 786432u + 12288u) {
    const unsigned r   = idx - 786432u;
    const unsigned kt  = (r >> 6) & 63u;
    const unsigned nsr = r >> 12;
    const unsigned o   = nsr * 16u + (lane & 15u);
    const unsigned k0  = kt * 32u + (lane >> 4) * 8u;
    unsigned hi[4], lo[4];
#pragma unroll
    for (int u2 = 0; u2 < 4; ++u2) {
      unsigned hb[2], lb[2];
#pragma unroll
      for (int c = 0; c < 2; ++c) {
        const unsigned k = k0 + 2u * (unsigned)u2 + (unsigned)c;
        float w = 0.0f;
        if (o < 32u)       w = w_out[(size_t)o * 2048u + k];
        else if (o == 32u) w = w_li[k];
        const unsigned h = bf16rne(w);
        const float hvf = __uint_as_float(h << 16);
        hb[c] = h;
        lb[c] = bf16rne(__fsub_rn(w, hvf));
      }
      hi[u2] = hb[0] | (hb[1] << 16);
      lo[u2] = lb[0] | (lb[1] << 16);
    }
    u32x4 vh, vl;
    vh[0]=hi[0]; vh[1]=hi[1]; vh[2]=hi[2]; vh[3]=hi[3];
    vl[0]=lo[0]; vl[1]=lo[1]; vl[2]=lo[2]; vl[3]=lo[3];
    wf[WR_BASE + r] = vh;
    wf[WR_BASE + WR_PLANE + r] = vl;
  }
}

// ---------------- main persistent ALIF kernel ----------------
// grid 256: wg = mh(2) x ns(128 slices of 16 neurons); 512 threads = 8 waves
// sync fused into data: tagged z words in 8-slot ring; one speculative load attempt
// at end of shadow, retry-only-on-failure with backoff. No grid barrier in loop.
extern "C" __global__ __launch_bounds__(512, 2) void k_main(
    const u32x4* __restrict__ wf,
    const unsigned char* __restrict__ xsb,
    unsigned* __restrict__ zroll,
    unsigned* __restrict__ bar,
    unsigned* __restrict__ fin,
    float* __restrict__ out)
{
  __shared__ unsigned abytes[64][100];   // z bits cols 0..63, xs bits cols 64..95
  __shared__ float red[8][64][17];
  __shared__ unsigned char zn[64][4];
  __shared__ float pad_lds[6000];        // force 1 wg/CU

  const unsigned tid  = threadIdx.x;
  const unsigned wg   = blockIdx.x;
  const unsigned mh   = wg >> 7;
  const unsigned ns   = wg & 127u;
  const unsigned wv   = tid >> 6;        // 0..7
  const unsigned lane = tid & 63u;
  const unsigned ln15 = lane & 15u;
  const unsigned g4   = lane >> 4;
  const unsigned selr = g4 * 0x01010101u;  // v_perm selector: splat byte g4
  const unsigned blq  = tid & 63u;
  const unsigned q    = tid >> 6;
  const bool     upd  = tid < 256u;
  const bool     dual = ns < 3u;

  if (tid == 0) ((volatile float*)pad_lds)[0] = 0.f;

  const u32x4* WH = wf + (size_t)ns * 6144u;
  const u32x4* WL = wf + WF_PLANE + (size_t)ns * 6144u;
  const u32x4* RH = wf + WR_BASE + (size_t)ns * 4096u;
  const u32x4* RL = wf + WR_BASE + WR_PLANE + (size_t)ns * 4096u;

  float v[4]  = {0,0,0,0}, a[4] = {0,0,0,0}, zf[4] = {0,0,0,0};
  float vo[4] = {0,0,0,0}, voMax[4] = {0,0,0,0};
  float liv = 0.f, lii = 0.f, liMax = 0.f;

  f32x4 accX0 = {0,0,0,0}, accX1 = {0,0,0,0}, accX2 = {0,0,0,0}, accX3 = {0,0,0,0};
  U4S8 bhZ[8], blZ[8];                   // resident z-part weights (64 VGPR)
  U4S8 bhX[4], blX[4];                   // resident xs-part weights (32 VGPR)
  u32x4 pzA, pzB;                        // pre-validated packed z for the current step
  const int zk = (int)wv * 8;
  const int xk = 64 + (int)wv * 4;

  auto pk = [](unsigned long long t) -> unsigned {
    return (unsigned)(t & 0xFFFFu) | (unsigned)(((t >> 32) & 0xFFFFu) << 16);
  };
  auto tagok = [](unsigned long long z, unsigned tg) -> bool {
    return (((unsigned)(z >> 16) & 0xFFFFu) == tg) &&
           (((unsigned)(z >> 48) & 0xFFFFu) == tg);
  };

  // per-wave xs staging: wave wv, lane l -> row l, cols [64+4wv, +4)
  auto stage_xs = [&](int t) {
    const unsigned char* xr = xsb + ((size_t)t * 128u + mh * 64u) * 128u;
    const u32x4 val = *(const u32x4*)(xr + (size_t)lane * 128u + wv * 16u);
    *(u32x4*)&abytes[lane][64u + wv * 4u] = val;
  };

  // fast decode: byte g4 of dw -> 4 packed bf16 {0,1} pairs
  auto mk = [&](unsigned dw, U4S8& af) {
    const unsigned sp = __builtin_amdgcn_perm(dw, dw, selr);            // splat byte g4
    const unsigned W  = ((sp >> 1) & 0xFFFF0000u) | (sp & 0x0000FFFFu); // lo=byte, hi=byte>>1
    af.w[0] = __umul24(W & 0x00010001u, 0x3F80u);
    af.w[1] = __umul24(W & 0x00040004u, 0x0FE0u);
    af.w[2] = __umul24(W & 0x00100010u, 0x03F8u);
    af.w[3] = __umul24(W & 0x00400040u, 0x00FEu);
  };

  auto dosub2 = [&](unsigned dw, const short8& bhj, const short8& blj, f32x4& ACC) {
    U4S8 af; mk(dw, af);
    ACC = __builtin_amdgcn_mfma_f32_16x16x32_bf16(af.s, bhj, ACC, 0, 0, 0);
    ACC = __builtin_amdgcn_mfma_f32_16x16x32_bf16(af.s, blj, ACC, 0, 0, 0);
  };

  // 4 kt x 4 row-blocks into accX0..3
  auto grp4 = [&](int kb, const U4S8* bh, const U4S8* bl) {
    U4S8 a0, a1, a2, a3;
    a0.u = *(const u32x4*)&abytes[ 0 + ln15][kb];
    a1.u = *(const u32x4*)&abytes[16 + ln15][kb];
    a2.u = *(const u32x4*)&abytes[32 + ln15][kb];
    a3.u = *(const u32x4*)&abytes[48 + ln15][kb];
#pragma unroll
    for (int j = 0; j < 4; ++j) {
      dosub2(a0.w[j], bh[j].s, bl[j].s, accX0);
      dosub2(a1.w[j], bh[j].s, bl[j].s, accX1);
      dosub2(a2.w[j], bh[j].s, bl[j].s, accX2);
      dosub2(a3.w[j], bh[j].s, bl[j].s, accX3);
    }
  };

  auto compute_accX = [&]() {   // xs part: kt xk..xk+4, resident weights
    accX0 = {0,0,0,0}; accX1 = {0,0,0,0}; accX2 = {0,0,0,0}; accX3 = {0,0,0,0};
    grp4(xk, bhX, blX);
  };

  // one speculative attempt; retry only while tags invalid (s_sleep backoff)
  auto spin_pack = [&](int t) {
    const unsigned tg = (unsigned)t & 0xFFFFu;
    const unsigned long long* zp = (const unsigned long long*)zroll +
        ((size_t)((((unsigned)t & 7u) * 2u + mh) * 64u + lane) * 64u) + (unsigned)zk;
    unsigned long long z0, z1, z2, z3, z4, z5, z6, z7;
    for (;;) {
      z0 = __hip_atomic_load(zp + 0, AT_RLX, SC_AGT);
      z1 = __hip_atomic_load(zp + 1, AT_RLX, SC_AGT);
      z2 = __hip_atomic_load(zp + 2, AT_RLX, SC_AGT);
      z3 = __hip_atomic_load(zp + 3, AT_RLX, SC_AGT);
      z4 = __hip_atomic_load(zp + 4, AT_RLX, SC_AGT);
      z5 = __hip_atomic_load(zp + 5, AT_RLX, SC_AGT);
      z6 = __hip_atomic_load(zp + 6, AT_RLX, SC_AGT);
      z7 = __hip_atomic_load(zp + 7, AT_RLX, SC_AGT);
      const bool ok = tagok(z0, tg) && tagok(z1, tg) && tagok(z2, tg) && tagok(z3, tg)
                   && tagok(z4, tg) && tagok(z5, tg) && tagok(z6, tg) && tagok(z7, tg);
      if (__all(ok ? 1 : 0)) break;
      __builtin_amdgcn_s_sleep(4);
    }
    pzA[0] = pk(z0); pzA[1] = pk(z1); pzA[2] = pk(z2); pzA[3] = pk(z3);
    pzB[0] = pk(z4); pzB[1] = pk(z5); pzB[2] = pk(z6); pzB[3] = pk(z7);
  };

  auto redstore = [&]() {
#pragma unroll
    for (int r = 0; r < 4; ++r) {
      red[wv][ 0 + g4 * 4 + r][ln15] = accX0[r];
      red[wv][16 + g4 * 4 + r][ln15] = accX1[r];
      red[wv][32 + g4 * 4 + r][ln15] = accX2[r];
      red[wv][48 + g4 * 4 + r][ln15] = accX3[r];
    }
  };

  auto readout_pass = [&]() {   // hi+lo readout of z in abytes cols zk..zk+8 (L2 weights)
    f32x4 r0 = {0,0,0,0}, r1 = {0,0,0,0}, r2 = {0,0,0,0}, r3 = {0,0,0,0};
    const int kb = (int)wv * 8;
#pragma unroll
    for (int kc = 0; kc < 8; kc += 4) {
      U4S8 ar0, ar1, ar2, ar3;
      ar0.u = *(const u32x4*)&abytes[ 0 + ln15][kb + kc];
      ar1.u = *(const u32x4*)&abytes[16 + ln15][kb + kc];
      ar2.u = *(const u32x4*)&abytes[32 + ln15][kb + kc];
      ar3.u = *(const u32x4*)&abytes[48 + ln15][kb + kc];
      U4S8 bh[4], bl[4];
#pragma unroll
      for (int j = 0; j < 4; ++j) {
        bh[j].u = RH[(size_t)(kb + kc + j) * 64u + lane];
        bl[j].u = RL[(size_t)(kb + kc + j) * 64u + lane];
      }
#pragma unroll
      for (int j = 0; j < 4; ++j) {
        U4S8 af0; mk(ar0.w[j], af0);
        r0 = __builtin_amdgcn_mfma_f32_16x16x32_bf16(af0.s, bh[j].s, r0, 0, 0, 0);
        r0 = __builtin_amdgcn_mfma_f32_16x16x32_bf16(af0.s, bl[j].s, r0, 0, 0, 0);
        U4S8 af1; mk(ar1.w[j], af1);
        r1 = __builtin_amdgcn_mfma_f32_16x16x32_bf16(af1.s, bh[j].s, r1, 0, 0, 0);
        r1 = __builtin_amdgcn_mfma_f32_16x16x32_bf16(af1.s, bl[j].s, r1, 0, 0, 0);
        U4S8 af2; mk(ar2.w[j], af2);
        r2 = __builtin_amdgcn_mfma_f32_16x16x32_bf16(af2.s, bh[j].s, r2, 0, 0, 0);
        r2 = __builtin_amdgcn_mfma_f32_16x16x32_bf16(af2.s, bl[j].s, r2, 0, 0, 0);
        U4S8 af3; mk(ar3.w[j], af3);
        r3 = __builtin_amdgcn_mfma_f32_16x16x32_bf16(af3.s, bh[j].s, r3, 0, 0, 0);
        r3 = __builtin_amdgcn_mfma_f32_16x16x32_bf16(af3.s, bl[j].s, r3, 0, 0, 0);
      }
    }
#pragma unroll
    for (int r = 0; r < 4; ++r) {
      red[wv][ 0 + g4 * 4 + r][ln15] = r0[r];
      red[wv][16 + g4 * 4 + r][ln15] = r1[r];
      red[wv][32 + g4 * 4 + r][ln15] = r2[r];
      red[wv][48 + g4 * 4 + r][ln15] = r3[r];
    }
    __syncthreads();
    if (upd) {
      if (ns < 2u) {
#pragma unroll
        for (int jj = 0; jj < 4; ++jj) {
          const unsigned n = q * 4u + (unsigned)jj;
          float s = ((red[0][blq][n] + red[1][blq][n]) + (red[2][blq][n] + red[3][blq][n]))
                  + ((red[4][blq][n] + red[5][blq][n]) + (red[6][blq][n] + red[7][blq][n]));
          vo[jj] = __fadd_rn(__fmul_rn(0.8f, vo[jj]), s);
          voMax[jj] = fmaxf(voMax[jj], vo[jj]);
        }
      } else if (q == 0u) {
        float s = ((red[0][blq][0] + red[1][blq][0]) + (red[2][blq][0] + red[3][blq][0]))
                + ((red[4][blq][0] + red[5][blq][0]) + (red[6][blq][0] + red[7][blq][0]));
        const float ij = __fadd_rn(lii, s);
        liv = __fadd_rn(liv, __fmul_rn(0.1f, __fsub_rn(ij, liv)));
        lii = __fsub_rn(ij, __fmul_rn(0.2f, ij));
        liMax = fmaxf(liMax, liv);
      }
    }
    __syncthreads();
  };

  // ---- prologue: resident weights (once), xs_0, accX(0), z_0 (memset zeros, tag 0) ----
#pragma unroll
  for (int j = 0; j < 8; ++j) {
    bhZ[j].u = WH[(size_t)(zk + j) * 64u + lane];
    blZ[j].u = WL[(size_t)(zk + j) * 64u + lane];
  }
#pragma unroll
  for (int j = 0; j < 4; ++j) {
    bhX[j].u = WH[(size_t)(xk + j) * 64u + lane];
    blX[j].u = WL[(size_t)(xk + j) * 64u + lane];
  }
  stage_xs(0);
  compute_accX();
  spin_pack(0);

  for (int t = 0; t < TSTEPS; ++t) {
    // ---- consume pre-validated z_t: LDS write + z-part MFMA from resident regs ----
    *(u32x4*)&abytes[lane][(unsigned)zk] = pzA;
    grp4(zk, &bhZ[0], &blZ[0]);
    *(u32x4*)&abytes[lane][(unsigned)zk + 4u] = pzB;
    grp4(zk + 4, &bhZ[4], &blZ[4]);
    redstore();
    __syncthreads();

    // ---- ALIF state update ----
    if (upd) {
      unsigned nib = 0u;
#pragma unroll
      for (int jj = 0; jj < 4; ++jj) {
        const unsigned n = q * 4u + (unsigned)jj;
        const float dv = ((red[0][blq][n] + red[1][blq][n]) + (red[2][blq][n] + red[3][blq][n]))
                       + ((red[4][blq][n] + red[5][blq][n]) + (red[6][blq][n] + red[7][blq][n]));
        const float vv = __fsub_rn(__fadd_rn(__fmul_rn(0.8f, v[jj]), dv),
                                   __fmul_rn(zf[jj], 0.6f));
        a[jj] = __fadd_rn(__fmul_rn(0.97f, a[jj]), zf[jj]);
        const float th = __fadd_rn(0.6f, __fmul_rn(0.07f, a[jj]));
        const bool znew = vv > th;
        zf[jj] = znew ? 1.0f : 0.0f;
        v[jj] = vv;
        nib |= (znew ? 1u : 0u) << jj;
      }
      zn[blq][q] = (unsigned char)nib;
    }
    __syncthreads();

    // ---- publish z_{t+1} with embedded tag (fire-and-forget) ----
    if (tid < 64u) {
      const unsigned m16 = (unsigned)zn[tid][0] | ((unsigned)zn[tid][1] << 4) |
                           ((unsigned)zn[tid][2] << 8) | ((unsigned)zn[tid][3] << 12);
      const unsigned word = m16 | (((unsigned)(t + 1) & 0xFFFFu) << 16);
      __hip_atomic_store(zroll + ((((unsigned)(t + 1) & 7u) * 2u + mh) * 64u + tid) * 128u + ns,
                         word, AT_RLX, SC_AGT);
    }

    // ---- shadow: xs_{t+1}, readout(z_t), accX(t+1); then speculative z_{t+1} load ----
    if (t < TSTEPS - 1) stage_xs(t + 1);
    if (dual && t > 0) readout_pass();
    if (t < TSTEPS - 1) compute_accX();
    if (dual || t < TSTEPS - 1) spin_pack(t + 1);
  }

  // ---- post-loop: readout of z_199 (pre-validated in pz) + outputs ----
  if (dual) {
    *(u32x4*)&abytes[lane][(unsigned)zk] = pzA;
    *(u32x4*)&abytes[lane][(unsigned)zk + 4u] = pzB;
    readout_pass();
    if (ns < 2u) {
      if (upd) {
#pragma unroll
        for (int jj = 0; jj < 4; ++jj) {
          __hip_atomic_store(fin + ((size_t)mh * 64u + blq) * 32u + ns * 16u + q * 4u + (unsigned)jj,
                             __float_as_uint(voMax[jj]), AT_RLX, SC_AGT);
        }
      }
      __syncthreads();   // drain fin stores before signaling
      if (tid == 0) __hip_atomic_fetch_add(bar + mh * 16u, 1u, AT_RLX, SC_AGT);
    }
    if (ns == 2u && tid < 64u) {
      out[4096u + mh * 64u + tid] = liMax;
    }
  }

  // ---- ns==0 wg of each domain: wait for ns0+ns1 fin, then softmax ----
  if (ns == 0u) {
    if (tid == 0) {
      while (__hip_atomic_load(bar + mh * 16u, AT_RLX, SC_AGT) < 2u) {
        __builtin_amdgcn_s_sleep(2);
      }
      asm volatile("" ::: "memory");
    }
    __syncthreads();
    if (tid < 64u) {
      const unsigned grow = mh * 64u + tid;
      float vals[32];
#pragma unroll
      for (int o = 0; o < 32; ++o)
        vals[o] = __uint_as_float(__hip_atomic_load(fin + (size_t)grow * 32u + o,
                                                    AT_RLX, SC_AGT));
      float mx = vals[0];
#pragma unroll
      for (int o = 1; o < 32; ++o) mx = fmaxf(mx, vals[o]);
      float ssum = 0.f;
#pragma unroll
      for (int o = 0; o < 32; ++o) ssum += expf(vals[o] - mx);
      const float inv = 1.0f / ssum;
#pragma unroll
      for (int o = 0; o < 32; ++o) out[(size_t)grow * 32u + o] = expf(vals[o] - mx) * inv;
    }
  }
}

// ---------------- launch ----------------
extern "C" void kernel_launch(void* const* d_in, const int* in_sizes, int n_in,
                              void* d_out, int out_size, void* d_ws, size_t ws_size,
                              hipStream_t stream)
{
  (void)in_sizes; (void)n_in; (void)out_size;
  if (ws_size < (size_t)WS_NEED) return;

  const float* x     = (const float*)d_in[0];
  const float* w_in  = (const float*)d_in[1];
  const float* w_rec = (const float*)d_in[2];
  const float* w_out = (const float*)d_in[3];
  const float* w_li  = (const float*)d_in[4];
  unsigned char* ws  = (unsigned char*)d_ws;

  unsigned*      bar   = (unsigned*)(ws + WS_BAR);
  unsigned*      zroll = (unsigned*)(ws + WS_ZROLL);
  unsigned*      fin   = (unsigned*)(ws + WS_FIN);
  unsigned char* xsb   = ws + WS_XSB;
  u32x4*         wf    = (u32x4*)(ws + WS_WF);

  hipMemsetAsync(ws, 0, 4096u + 524288u, stream);   // bar + zroll (tags cleared)
  k_encode<<<dim3(128), dim3(1024), 0, stream>>>(x, xsb);
  k_prep<<<dim3(3120), dim3(256), 0, stream>>>(w_rec, w_in, w_out, w_li, wf);
  k_main<<<dim3(256), dim3(512), 0, stream>>>(wf, xsb, zroll, bar, fin, (float*)d_out);
}

// Round 10
// 1567.116 us; speedup vs baseline: 1.3843x; 1.3843x over previous
//
#include <hip/hip_runtime.h>
#include <cstdint>
#include <cstddef>

typedef __attribute__((ext_vector_type(8))) short short8;
typedef __attribute__((ext_vector_type(4))) float f32x4;
typedef __attribute__((ext_vector_type(4))) unsigned int u32x4;

union U4S8 { u32x4 u; short8 s; unsigned w[4]; };

#define TSTEPS 199

#define WF_PLANE 786432u    // u32x4 per main plane (128 slices x 96 kt x 64 lanes)
#define WR_BASE  1572864u   // u32x4 index where readout frags start
#define WR_PLANE 12288u     // 3 slices x 64 kt x 64 lanes (hi plane; lo follows)

// ---- workspace layout (bytes) ----
#define WS_BAR  0u           // 2 domains x 1 KB group counters (8 x 64B-spaced each)
#define WS_ZB   4096u        // 2 buf x 2 mh x 64 row x 128 ns u32  = 128 KB
#define WS_FIN  135168u      // 128 x 32 f32 voMax = 16 KB
#define WS_XSB  151552u      // 199 x 128 x 128 B encoder bits
#define WS_WF   3411968u     // (1572864 + 2*12288) x 16 B fragments
#define WS_NEED 28971008u

#define AT_RLX __ATOMIC_RELAXED
#define SC_AGT __HIP_MEMORY_SCOPE_AGENT

// ---------------- encoder: constant-current LIF -> spike bit rows ----------------
extern "C" __global__ __launch_bounds__(1024) void k_encode(
    const float* __restrict__ x, unsigned char* __restrict__ xsb)
{
  const int b = blockIdx.x;
  const int tid = threadIdx.x;
  const float xv = (tid < 512) ? x[b * 512 + tid] : x[b * 512 + tid - 512];
  const float I = (tid < 512) ? fmaxf(__fmul_rn(50.0f, xv), 0.0f)
                              : fmaxf(__fmul_rn(-50.0f, xv), 0.0f);
  float v = 0.0f;
  unsigned long long* dst =
      (unsigned long long*)(xsb + (size_t)b * 128u + (size_t)(tid >> 6) * 8u);
  for (int t = 0; t < TSTEPS; ++t) {
    v = __fadd_rn(v, __fmul_rn(0.1f, __fsub_rn(I, v)));
    const bool z = v > 1.0f;
    if (z) v = 0.0f;
    const unsigned long long m = __ballot(z ? 1 : 0);
    if ((tid & 63) == 0) dst[(size_t)t * 2048u] = m;
  }
}

// ---------------- weight prep: hi/lo bf16 split into MFMA-fragment order ----------------
__device__ __forceinline__ unsigned bf16rne(float f) {
  const unsigned u = __float_as_uint(f);
  return ((u + 0x7FFFu + ((u >> 16) & 1u)) >> 16) & 0xFFFFu;
}

extern "C" __global__ __launch_bounds__(256) void k_prep(
    const float* __restrict__ w_rec, const float* __restrict__ w_in,
    const float* __restrict__ w_out, const float* __restrict__ w_li,
    u32x4* __restrict__ wf)
{
  const unsigned idx  = blockIdx.x * 256u + threadIdx.x;
  const unsigned lane = idx & 63u;
  if (idx < 786432u) {
    const unsigned kt = (idx >> 6) % 96u;
    const unsigned ns = idx / 6144u;
    const unsigned j  = ns * 16u + (lane & 15u);
    const unsigned k0 = kt * 32u + (lane >> 4) * 8u;
    unsigned hi[4], lo[4];
#pragma unroll
    for (int u2 = 0; u2 < 4; ++u2) {
      unsigned hb[2], lb[2];
#pragma unroll
      for (int c = 0; c < 2; ++c) {
        const unsigned k = k0 + 2u * (unsigned)u2 + (unsigned)c;
        float w;
        if (k < 2048u) w = (k == j) ? 0.0f : w_rec[(size_t)j * 2048u + k];
        else           w = w_in[(size_t)j * 1024u + (k - 2048u)];
        const unsigned h = bf16rne(w);
        const float hvf = __uint_as_float(h << 16);
        const unsigned l = bf16rne(__fsub_rn(w, hvf));
        hb[c] = h; lb[c] = l;
      }
      hi[u2] = hb[0] | (hb[1] << 16);
      lo[u2] = lb[0] | (lb[1] << 16);
    }
    u32x4 vh, vl;
    vh[0]=hi[0]; vh[1]=hi[1]; vh[2]=hi[2]; vh[3]=hi[3];
    vl[0]=lo[0]; vl[1]=lo[1]; vl[2]=lo[2]; vl[3]=lo[3];
    wf[idx] = vh;
    wf[idx + WF_PLANE] = vl;
  } else if (idx < 786432u + 12288u) {
    const unsigned r   = idx - 786432u;
    const unsigned kt  = (r >> 6) & 63u;
    const unsigned nsr = r >> 12;
    const unsigned o   = nsr * 16u + (lane & 15u);
    const unsigned k0  = kt * 32u + (lane >> 4) * 8u;
    unsigned hi[4], lo[4];
#pragma unroll
    for (int u2 = 0; u2 < 4; ++u2) {
      unsigned hb[2], lb[2];
#pragma unroll
      for (int c = 0; c < 2; ++c) {
        const unsigned k = k0 + 2u * (unsigned)u2 + (unsigned)c;
        float w = 0.0f;
        if (o < 32u)       w = w_out[(size_t)o * 2048u + k];
        else if (o == 32u) w = w_li[k];
        const unsigned h = bf16rne(w);
        const float hvf = __uint_as_float(h << 16);
        hb[c] = h;
        lb[c] = bf16rne(__fsub_rn(w, hvf));
      }
      hi[u2] = hb[0] | (hb[1] << 16);
      lo[u2] = lb[0] | (lb[1] << 16);
    }
    u32x4 vh, vl;
    vh[0]=hi[0]; vh[1]=hi[1]; vh[2]=hi[2]; vh[3]=hi[3];
    vl[0]=lo[0]; vl[1]=lo[1]; vl[2]=lo[2]; vl[3]=lo[3];
    wf[WR_BASE + r] = vh;
    wf[WR_BASE + WR_PLANE + r] = vl;
  }
}

// ---------------- flat decoupled barrier: 8 group counters, tid0-only spin ----------------
__device__ __forceinline__ void bar_arrive(unsigned* dbar, unsigned ns)
{
  __syncthreads();   // drain this wg's vmem (zb publish acked) before signaling
  if (threadIdx.x == 0) {
    __hip_atomic_fetch_add(dbar + (ns >> 4) * 16u, 1u, AT_RLX, SC_AGT);
  }
}

__device__ __forceinline__ void bar_wait16(unsigned* dbar, unsigned tgt16)
{
  if (threadIdx.x == 0) {
    for (;;) {
      unsigned mn = 0xFFFFFFFFu;
#pragma unroll
      for (int g = 0; g < 8; ++g) {
        const unsigned c = __hip_atomic_load(dbar + g * 16, AT_RLX, SC_AGT);
        mn = (c < mn) ? c : mn;
      }
      if (mn >= tgt16) break;
      __builtin_amdgcn_s_sleep(1);
    }
    asm volatile("" ::: "memory");
  }
  __syncthreads();
}

// ---------------- main persistent ALIF kernel ----------------
// grid 256: wg = mh(2 domains) x ns(128 slices of 16 neurons); 512 threads = 8 waves
// per-wave staging; ALL main-loop weights resident in VGPRs; hi-only readout shadow
extern "C" __global__ __launch_bounds__(512, 2) void k_main(
    const u32x4* __restrict__ wf,
    const unsigned char* __restrict__ xsb,
    unsigned* __restrict__ zb,
    unsigned* __restrict__ bar,
    unsigned* __restrict__ fin,
    float* __restrict__ out)
{
  __shared__ unsigned abytes[64][100];   // z bits cols 0..63, xs bits cols 64..95
  __shared__ float red[8][64][17];
  __shared__ unsigned char zn[64][4];
  __shared__ float pad_lds[6000];        // force 1 wg/CU

  const unsigned tid  = threadIdx.x;
  const unsigned wg   = blockIdx.x;
  const unsigned mh   = wg >> 7;
  const unsigned ns   = wg & 127u;
  const unsigned wv   = tid >> 6;        // 0..7
  const unsigned lane = tid & 63u;
  const unsigned ln15 = lane & 15u;
  const unsigned g4   = lane >> 4;
  const unsigned selr = g4 * 0x01010101u;  // v_perm selector: splat byte g4
  const unsigned blq  = tid & 63u;
  const unsigned q    = tid >> 6;
  const bool     upd  = tid < 256u;
  const bool     dual = ns < 3u;

  if (tid == 0) ((volatile float*)pad_lds)[0] = 0.f;

  unsigned* dbar = bar + mh * 256u;

  const u32x4* WH = wf + (size_t)ns * 6144u;
  const u32x4* WL = wf + WF_PLANE + (size_t)ns * 6144u;
  const u32x4* RH = wf + WR_BASE + (size_t)ns * 4096u;

  float v[4]  = {0,0,0,0}, a[4] = {0,0,0,0}, zf[4] = {0,0,0,0};
  float vo[4] = {0,0,0,0}, voMax[4] = {0,0,0,0};
  float liv = 0.f, lii = 0.f, liMax = 0.f;

  f32x4 accX0 = {0,0,0,0}, accX1 = {0,0,0,0}, accX2 = {0,0,0,0}, accX3 = {0,0,0,0};
  U4S8 bhZ[8], blZ[8];                   // resident z-part weights (64 VGPR)
  U4S8 bhX[4], blX[4];                   // resident xs-part weights (32 VGPR)
  const int zk = (int)wv * 8;
  const int xk = 64 + (int)wv * 4;

  auto pk = [](unsigned long long t) -> unsigned {
    return (unsigned)(t & 0xFFFFu) | (unsigned)(((t >> 32) & 0xFFFFu) << 16);
  };

  // per-wave xs staging: wave wv, lane l -> row l, cols [64+4wv, +4)
  auto stage_xs = [&](int t) {
    const unsigned char* xr = xsb + ((size_t)t * 128u + mh * 64u) * 128u;
    const u32x4 val = *(const u32x4*)(xr + (size_t)lane * 128u + wv * 16u);
    *(u32x4*)&abytes[lane][64u + wv * 4u] = val;
  };

  // fast decode: byte g4 of dw -> 4 packed bf16 {0,1} pairs
  auto mk = [&](unsigned dw, U4S8& af) {
    const unsigned sp = __builtin_amdgcn_perm(dw, dw, selr);            // splat byte g4
    const unsigned W  = ((sp >> 1) & 0xFFFF0000u) | (sp & 0x0000FFFFu); // lo=byte, hi=byte>>1
    af.w[0] = __umul24(W & 0x00010001u, 0x3F80u);
    af.w[1] = __umul24(W & 0x00040004u, 0x0FE0u);
    af.w[2] = __umul24(W & 0x00100010u, 0x03F8u);
    af.w[3] = __umul24(W & 0x00400040u, 0x00FEu);
  };

  auto dosub2 = [&](unsigned dw, const short8& bhj, const short8& blj, f32x4& ACC) {
    U4S8 af; mk(dw, af);
    ACC = __builtin_amdgcn_mfma_f32_16x16x32_bf16(af.s, bhj, ACC, 0, 0, 0);
    ACC = __builtin_amdgcn_mfma_f32_16x16x32_bf16(af.s, blj, ACC, 0, 0, 0);
  };

  // 4 kt x 4 row-blocks into accX0..3
  auto grp4 = [&](int kb, const U4S8* bh, const U4S8* bl) {
    U4S8 a0, a1, a2, a3;
    a0.u = *(const u32x4*)&abytes[ 0 + ln15][kb];
    a1.u = *(const u32x4*)&abytes[16 + ln15][kb];
    a2.u = *(const u32x4*)&abytes[32 + ln15][kb];
    a3.u = *(const u32x4*)&abytes[48 + ln15][kb];
#pragma unroll
    for (int j = 0; j < 4; ++j) {
      dosub2(a0.w[j], bh[j].s, bl[j].s, accX0);
      dosub2(a1.w[j], bh[j].s, bl[j].s, accX1);
      dosub2(a2.w[j], bh[j].s, bl[j].s, accX2);
      dosub2(a3.w[j], bh[j].s, bl[j].s, accX3);
    }
  };

  auto compute_accX = [&]() {   // xs part: kt xk..xk+4, resident weights
    accX0 = {0,0,0,0}; accX1 = {0,0,0,0}; accX2 = {0,0,0,0}; accX3 = {0,0,0,0};
    grp4(xk, bhX, blX);
  };

  // stage this wave's z cols (8 u64 agent loads) interleaved with the z-part MFMA
  auto stage_and_zpart = [&](unsigned buf) {
    const unsigned long long* zp = (const unsigned long long*)zb +
        ((size_t)((buf * 2u + mh) * 64u + lane) * 64u) + (unsigned)zk;
    unsigned long long z0 = __hip_atomic_load(zp + 0, AT_RLX, SC_AGT);
    unsigned long long z1 = __hip_atomic_load(zp + 1, AT_RLX, SC_AGT);
    unsigned long long z2 = __hip_atomic_load(zp + 2, AT_RLX, SC_AGT);
    unsigned long long z3 = __hip_atomic_load(zp + 3, AT_RLX, SC_AGT);
    unsigned long long z4 = __hip_atomic_load(zp + 4, AT_RLX, SC_AGT);
    unsigned long long z5 = __hip_atomic_load(zp + 5, AT_RLX, SC_AGT);
    unsigned long long z6 = __hip_atomic_load(zp + 6, AT_RLX, SC_AGT);
    unsigned long long z7 = __hip_atomic_load(zp + 7, AT_RLX, SC_AGT);
    u32x4 wa; wa[0] = pk(z0); wa[1] = pk(z1); wa[2] = pk(z2); wa[3] = pk(z3);
    *(u32x4*)&abytes[lane][(unsigned)zk] = wa;
    grp4(zk, &bhZ[0], &blZ[0]);          // chunk A MFMA hides chunk B load tail
    u32x4 wb; wb[0] = pk(z4); wb[1] = pk(z5); wb[2] = pk(z6); wb[3] = pk(z7);
    *(u32x4*)&abytes[lane][(unsigned)zk + 4u] = wb;
    grp4(zk + 4, &bhZ[4], &blZ[4]);
  };

  auto redstore = [&]() {
#pragma unroll
    for (int r = 0; r < 4; ++r) {
      red[wv][ 0 + g4 * 4 + r][ln15] = accX0[r];
      red[wv][16 + g4 * 4 + r][ln15] = accX1[r];
      red[wv][32 + g4 * 4 + r][ln15] = accX2[r];
      red[wv][48 + g4 * 4 + r][ln15] = accX3[r];
    }
  };

  auto readout_pass = [&]() {   // hi-only readout of z in abytes cols zk..zk+8
    f32x4 r0 = {0,0,0,0}, r1 = {0,0,0,0}, r2 = {0,0,0,0}, r3 = {0,0,0,0};
    const int kb = (int)wv * 8;
#pragma unroll
    for (int kc = 0; kc < 8; kc += 4) {
      U4S8 ar0, ar1, ar2, ar3;
      ar0.u = *(const u32x4*)&abytes[ 0 + ln15][kb + kc];
      ar1.u = *(const u32x4*)&abytes[16 + ln15][kb + kc];
      ar2.u = *(const u32x4*)&abytes[32 + ln15][kb + kc];
      ar3.u = *(const u32x4*)&abytes[48 + ln15][kb + kc];
      U4S8 bh[4];
#pragma unroll
      for (int j = 0; j < 4; ++j) {
        bh[j].u = RH[(size_t)(kb + kc + j) * 64u + lane];
      }
#pragma unroll
      for (int j = 0; j < 4; ++j) {
        U4S8 af0; mk(ar0.w[j], af0);
        r0 = __builtin_amdgcn_mfma_f32_16x16x32_bf16(af0.s, bh[j].s, r0, 0, 0, 0);
        U4S8 af1; mk(ar1.w[j], af1);
        r1 = __builtin_amdgcn_mfma_f32_16x16x32_bf16(af1.s, bh[j].s, r1, 0, 0, 0);
        U4S8 af2; mk(ar2.w[j], af2);
        r2 = __builtin_amdgcn_mfma_f32_16x16x32_bf16(af2.s, bh[j].s, r2, 0, 0, 0);
        U4S8 af3; mk(ar3.w[j], af3);
        r3 = __builtin_amdgcn_mfma_f32_16x16x32_bf16(af3.s, bh[j].s, r3, 0, 0, 0);
      }
    }
#pragma unroll
    for (int r = 0; r < 4; ++r) {
      red[wv][ 0 + g4 * 4 + r][ln15] = r0[r];
      red[wv][16 + g4 * 4 + r][ln15] = r1[r];
      red[wv][32 + g4 * 4 + r][ln15] = r2[r];
      red[wv][48 + g4 * 4 + r][ln15] = r3[r];
    }
    __syncthreads();
    if (upd) {
      if (ns < 2u) {
#pragma unroll
        for (int jj = 0; jj < 4; ++jj) {
          const unsigned n = q * 4u + (unsigned)jj;
          float s = ((red[0][blq][n] + red[1][blq][n]) + (red[2][blq][n] + red[3][blq][n]))
                  + ((red[4][blq][n] + red[5][blq][n]) + (red[6][blq][n] + red[7][blq][n]));
          vo[jj] = __fadd_rn(__fmul_rn(0.8f, vo[jj]), s);
          voMax[jj] = fmaxf(voMax[jj], vo[jj]);
        }
      } else if (q == 0u) {
        float s = ((red[0][blq][0] + red[1][blq][0]) + (red[2][blq][0] + red[3][blq][0]))
                + ((red[4][blq][0] + red[5][blq][0]) + (red[6][blq][0] + red[7][blq][0]));
        const float ij = __fadd_rn(lii, s);
        liv = __fadd_rn(liv, __fmul_rn(0.1f, __fsub_rn(ij, liv)));
        lii = __fsub_rn(ij, __fmul_rn(0.2f, ij));
        liMax = fmaxf(liMax, liv);
      }
    }
    __syncthreads();
  };

  // ---- prologue: resident weights (once), xs_0, accX(0) ----
#pragma unroll
  for (int j = 0; j < 8; ++j) {
    bhZ[j].u = WH[(size_t)(zk + j) * 64u + lane];
    blZ[j].u = WL[(size_t)(zk + j) * 64u + lane];
  }
#pragma unroll
  for (int j = 0; j < 4; ++j) {
    bhX[j].u = WH[(size_t)(xk + j) * 64u + lane];
    blX[j].u = WL[(size_t)(xk + j) * 64u + lane];
  }
  stage_xs(0);
  compute_accX();

  for (int t = 0; t < TSTEPS; ++t) {
    if (t > 0) bar_wait16(dbar, 16u * (unsigned)t);

    // ---- per-wave z stage + z-part MFMA from resident registers ----
    stage_and_zpart((unsigned)t & 1u);
    redstore();
    __syncthreads();

    // ---- ALIF state update ----
    if (upd) {
      unsigned nib = 0u;
#pragma unroll
      for (int jj = 0; jj < 4; ++jj) {
        const unsigned n = q * 4u + (unsigned)jj;
        const float dv = ((red[0][blq][n] + red[1][blq][n]) + (red[2][blq][n] + red[3][blq][n]))
                       + ((red[4][blq][n] + red[5][blq][n]) + (red[6][blq][n] + red[7][blq][n]));
        const float vv = __fsub_rn(__fadd_rn(__fmul_rn(0.8f, v[jj]), dv),
                                   __fmul_rn(zf[jj], 0.6f));
        a[jj] = __fadd_rn(__fmul_rn(0.97f, a[jj]), zf[jj]);
        const float th = __fadd_rn(0.6f, __fmul_rn(0.07f, a[jj]));
        const bool znew = vv > th;
        zf[jj] = znew ? 1.0f : 0.0f;
        v[jj] = vv;
        nib |= (znew ? 1u : 0u) << jj;
      }
      zn[blq][q] = (unsigned char)nib;
    }
    __syncthreads();

    // ---- publish z_{t+1} ----
    if (tid < 64u) {
      const unsigned m16 = (unsigned)zn[tid][0] | ((unsigned)zn[tid][1] << 4) |
                           ((unsigned)zn[tid][2] << 8) | ((unsigned)zn[tid][3] << 12);
      const unsigned nb = ((unsigned)t & 1u) ^ 1u;
      __hip_atomic_store(zb + ((nb * 2u + mh) * 64u + tid) * 128u + ns, m16,
                         AT_RLX, SC_AGT);
    }
    bar_arrive(dbar, ns);

    // ---- barrier shadow: xs_{t+1}, readout(z_t), accX(t+1) — no weight loads ----
    if (t < TSTEPS - 1) stage_xs(t + 1);
    if (dual && t > 0) readout_pass();
    if (t < TSTEPS - 1) compute_accX();
  }

  // ---- post-loop: readout of z_199 + publish results ----
  bar_wait16(dbar, 16u * (unsigned)TSTEPS);
  if (dual) {
    const unsigned buf = (unsigned)TSTEPS & 1u;
    const unsigned long long* zp = (const unsigned long long*)zb +
        ((size_t)((buf * 2u + mh) * 64u + lane) * 64u) + (unsigned)zk;
    u32x4 wa, wb;
    wa[0] = pk(__hip_atomic_load(zp + 0, AT_RLX, SC_AGT));
    wa[1] = pk(__hip_atomic_load(zp + 1, AT_RLX, SC_AGT));
    wa[2] = pk(__hip_atomic_load(zp + 2, AT_RLX, SC_AGT));
    wa[3] = pk(__hip_atomic_load(zp + 3, AT_RLX, SC_AGT));
    wb[0] = pk(__hip_atomic_load(zp + 4, AT_RLX, SC_AGT));
    wb[1] = pk(__hip_atomic_load(zp + 5, AT_RLX, SC_AGT));
    wb[2] = pk(__hip_atomic_load(zp + 6, AT_RLX, SC_AGT));
    wb[3] = pk(__hip_atomic_load(zp + 7, AT_RLX, SC_AGT));
    *(u32x4*)&abytes[lane][(unsigned)zk] = wa;
    *(u32x4*)&abytes[lane][(unsigned)zk + 4u] = wb;
    readout_pass();
    if (ns < 2u && upd) {
#pragma unroll
      for (int jj = 0; jj < 4; ++jj) {
        __hip_atomic_store(fin + ((size_t)mh * 64u + blq) * 32u + ns * 16u + q * 4u + (unsigned)jj,
                           __float_as_uint(voMax[jj]), AT_RLX, SC_AGT);
      }
    }
    if (ns == 2u && tid < 64u) {
      out[4096u + mh * 64u + tid] = liMax;
    }
  }
  bar_arrive(dbar, ns);

  // ---- ns==0 wg of each domain: softmax over its 64 rows ----
  if (ns == 0u) {
    bar_wait16(dbar, 16u * ((unsigned)TSTEPS + 1u));
    if (tid < 64u) {
      const unsigned grow = mh * 64u + tid;
      float vals[32];
#pragma unroll
      for (int o = 0; o < 32; ++o)
        vals[o] = __uint_as_float(__hip_atomic_load(fin + (size_t)grow * 32u + o,
                                                    AT_RLX, SC_AGT));
      float mx = vals[0];
#pragma unroll
      for (int o = 1; o < 32; ++o) mx = fmaxf(mx, vals[o]);
      float ssum = 0.f;
#pragma unroll
      for (int o = 0; o < 32; ++o) ssum += expf(vals[o] - mx);
      const float inv = 1.0f / ssum;
#pragma unroll
      for (int o = 0; o < 32; ++o) out[(size_t)grow * 32u + o] = expf(vals[o] - mx) * inv;
    }
  }
}

// ---------------- launch ----------------
extern "C" void kernel_launch(void* const* d_in, const int* in_sizes, int n_in,
                              void* d_out, int out_size, void* d_ws, size_t ws_size,
                              hipStream_t stream)
{
  (void)in_sizes; (void)n_in; (void)out_size;
  if (ws_size < (size_t)WS_NEED) return;

  const float* x     = (const float*)d_in[0];
  const float* w_in  = (const float*)d_in[1];
  const float* w_rec = (const float*)d_in[2];
  const float* w_out = (const float*)d_in[3];
  const float* w_li  = (const float*)d_in[4];
  unsigned char* ws  = (unsigned char*)d_ws;

  unsigned*      bar  = (unsigned*)(ws + WS_BAR);
  unsigned*      zb   = (unsigned*)(ws + WS_ZB);
  unsigned*      fin  = (unsigned*)(ws + WS_FIN);
  unsigned char* xsb  = ws + WS_XSB;
  u32x4*         wf   = (u32x4*)(ws + WS_WF);

  hipMemsetAsync(ws, 0, 4096u + 131072u, stream);   // bar + zb
  k_encode<<<dim3(128), dim3(1024), 0, stream>>>(x, xsb);
  k_prep<<<dim3(3120), dim3(256), 0, stream>>>(w_rec, w_in, w_out, w_li, wf);
  k_main<<<dim3(256), dim3(512), 0, stream>>>(wf, xsb, zb, bar, fin, (float*)d_out);
}